// Round 2
// baseline (1462.363 us; speedup 1.0000x reference)
//
#include <hip/hip_runtime.h>
#include <cstdint>
#include <cstddef>

// ---- problem constants ----
constexpr int Bn     = 512;
constexpr int Dd     = 11;
constexpr int LEAVES = 1024;
constexpr int NINT   = 1023;
constexpr int FLEAF  = 64;
constexpr int FINT   = 32;
constexpr int Hh     = 128;
constexpr int OUTC   = 33;

#define THREADS 256
constexpr int KSTR  = 136;            // LDS/weight k-stride (u16): 272B rows, 16B aligned
constexpr int MATSZ = 128 * KSTR;     // u16 per half-matrix (hi or lo)

using short8 = __attribute__((ext_vector_type(8))) short;
using f32x4  = __attribute__((ext_vector_type(4))) float;

__device__ __forceinline__ unsigned int f2bf_rne_u(float f) {
  unsigned int u = __float_as_uint(f);
  u += 0x7fffu + ((u >> 16) & 1);
  return u;                            // bf16 in hi16
}
__device__ __forceinline__ unsigned short f2bf_rne(float f) {
  return (unsigned short)(f2bf_rne_u(f) >> 16);
}
__device__ __forceinline__ float bf2f(unsigned short h) {
  return __uint_as_float((unsigned int)h << 16);
}
__device__ __forceinline__ float trunc_bf(float a) {
  return __uint_as_float(__float_as_uint(a) & 0xffff0000u);
}
// hi(trunc) of a -> lo16, hi(trunc) of b -> hi16
__device__ __forceinline__ unsigned int pack_hi_trunc(float a, float b) {
  return (__float_as_uint(a) >> 16) | (__float_as_uint(b) & 0xffff0000u);
}
// RNE-bf16 of a -> lo16, RNE-bf16 of b -> hi16 (HW packed convert, 1 instr)
__device__ __forceinline__ unsigned int pack_lo_rne(float a, float b) {
  unsigned int r;
  asm("v_cvt_pk_bf16_f32 %0, %1, %2" : "=v"(r) : "v"(a), "v"(b));
  return r;
}

// Swapped-operand dense layer: D = W_tile x Act^T.
// A-operand = WT[n][k] (n=l16 row), B-operand = Act[m][k] (m=l16 col).
// D: col = m = l16, row = n = quad*4+reg  -> epilogue writes 4 consecutive n (k of next
// layer) per fragment -> packed b64 LDS writes. ReLU(Act @ W + bias) in place.
//
// Pipelined: W hi+lo preloaded per layer (off the kc critical path; compiler may
// rematerialize some — fine, VGPR must stay <=128 for 4 waves/SIMD); ah double-buffered
// one kc ahead; al loaded at kc top, consumed by the LAST MFMA group (its LDS latency
// hides under the first two groups).
template <int KC, int MT>
__device__ __forceinline__ void dense_layer(
    unsigned short* Ah, unsigned short* Al,
    const unsigned short* __restrict__ WTh, const unsigned short* __restrict__ WTl,
    const float* __restrict__ bias)
{
  const int tid  = threadIdx.x;
  const int wave = tid >> 6;
  const int lane = tid & 63;
  const int quad = lane >> 4;
  const int l16  = lane & 15;
  const int nbase = wave * 32;

  // full W preload: hi AND lo fragments for this wave's 32-N slice
  short8 wh[2][KC], wl[2][KC];
#pragma unroll
  for (int nt = 0; nt < 2; ++nt) {
    const int n = nbase + nt * 16 + l16;
#pragma unroll
    for (int kc = 0; kc < KC; ++kc) {
      wh[nt][kc] = *(const short8*)&WTh[n * KSTR + kc * 32 + quad * 8];
      wl[nt][kc] = *(const short8*)&WTl[n * KSTR + kc * 32 + quad * 8];
    }
  }

  f32x4 c[MT][2];
#pragma unroll
  for (int mt = 0; mt < MT; ++mt)
#pragma unroll
    for (int nt = 0; nt < 2; ++nt) c[mt][nt] = (f32x4){0.f, 0.f, 0.f, 0.f};

  short8 ah[2][MT];   // double-buffered (index kc&1: static after full unroll)
  short8 al[MT];      // single-buffered, consumed by last group of same kc
#pragma unroll
  for (int mt = 0; mt < MT; ++mt)
    ah[0][mt] = *(const short8*)&Ah[(mt * 16 + l16) * KSTR + quad * 8];

#pragma unroll
  for (int kc = 0; kc < KC; ++kc) {
    const int cur = kc & 1;
    const int k0  = kc * 32 + quad * 8;
    // al for THIS kc (needed after 16 MFMAs)
#pragma unroll
    for (int mt = 0; mt < MT; ++mt)
      al[mt] = *(const short8*)&Al[(mt * 16 + l16) * KSTR + k0];
    // prefetch ah for NEXT kc
    if (kc + 1 < KC) {
      const int k1 = k0 + 32;
#pragma unroll
      for (int mt = 0; mt < MT; ++mt)
        ah[cur ^ 1][mt] = *(const short8*)&Ah[(mt * 16 + l16) * KSTR + k1];
    }
    __builtin_amdgcn_s_setprio(1);
#pragma unroll
    for (int mt = 0; mt < MT; ++mt)
#pragma unroll
      for (int nt = 0; nt < 2; ++nt)
        c[mt][nt] = __builtin_amdgcn_mfma_f32_16x16x32_bf16(wh[nt][kc], ah[cur][mt], c[mt][nt], 0, 0, 0);
#pragma unroll
    for (int mt = 0; mt < MT; ++mt)
#pragma unroll
      for (int nt = 0; nt < 2; ++nt)
        c[mt][nt] = __builtin_amdgcn_mfma_f32_16x16x32_bf16(wl[nt][kc], ah[cur][mt], c[mt][nt], 0, 0, 0);
#pragma unroll
    for (int mt = 0; mt < MT; ++mt)
#pragma unroll
      for (int nt = 0; nt < 2; ++nt)
        c[mt][nt] = __builtin_amdgcn_mfma_f32_16x16x32_bf16(wh[nt][kc], al[mt], c[mt][nt], 0, 0, 0);
    __builtin_amdgcn_s_setprio(0);
  }
  __syncthreads();  // all reads of Ah/Al done before in-place overwrite

  // bias loaded here: W/A fragment registers are dead, pressure is low
  float4 bv[2];
#pragma unroll
  for (int nt = 0; nt < 2; ++nt)
    bv[nt] = *(const float4*)&bias[nbase + nt * 16 + quad * 4];

#pragma unroll
  for (int mt = 0; mt < MT; ++mt) {
    const int m = mt * 16 + l16;
#pragma unroll
    for (int nt = 0; nt < 2; ++nt) {
      const int nb = nbase + nt * 16 + quad * 4;
      float v0 = fmaxf(c[mt][nt][0] + bv[nt].x, 0.f);
      float v1 = fmaxf(c[mt][nt][1] + bv[nt].y, 0.f);
      float v2 = fmaxf(c[mt][nt][2] + bv[nt].z, 0.f);
      float v3 = fmaxf(c[mt][nt][3] + bv[nt].w, 0.f);
      const unsigned int h0 = pack_hi_trunc(v0, v1);
      const unsigned int h1 = pack_hi_trunc(v2, v3);
      const unsigned int l0 = pack_lo_rne(v0 - trunc_bf(v0), v1 - trunc_bf(v1));
      const unsigned int l1 = pack_lo_rne(v2 - trunc_bf(v2), v3 - trunc_bf(v3));
      *(uint2*)&Ah[m * KSTR + nb] = make_uint2(h0, h1);
      *(uint2*)&Al[m * KSTR + nb] = make_uint2(l0, l1);
    }
  }
  __syncthreads();
}

// Output layer: [M x 128] @ [128 x 33] + bias (linear). Writes u16 hi/lo rows (stride 33)
// to outH/outL (global or LDS); optionally writes fp32 scalar (m=0,n=0) to finalOut.
template <int MT>
__device__ __forceinline__ void out_layer(
    const unsigned short* Ah, const unsigned short* Al,
    const unsigned short* __restrict__ WTh, const unsigned short* __restrict__ WTl,
    const float* __restrict__ bias,
    unsigned short* outH, unsigned short* outL, float* finalOut)
{
  const int tid  = threadIdx.x;
  const int wave = tid >> 6;
  const int lane = tid & 63;
  const int quad = lane >> 4;
  const int l16  = lane & 15;
  if (wave < 3) {                       // 48 padded cols cover 33
    const int n_row = wave * 16 + l16;
    short8 wh[4], wl[4];
#pragma unroll
    for (int kc = 0; kc < 4; ++kc) {
      wh[kc] = *(const short8*)&WTh[n_row * KSTR + kc * 32 + quad * 8];
      wl[kc] = *(const short8*)&WTl[n_row * KSTR + kc * 32 + quad * 8];
    }
    const int nb = wave * 16 + quad * 4;
    const float4 bv = *(const float4*)&bias[nb];
    const float bvr[4] = {bv.x, bv.y, bv.z, bv.w};

    f32x4 c[MT];
#pragma unroll
    for (int mt = 0; mt < MT; ++mt) c[mt] = (f32x4){0.f, 0.f, 0.f, 0.f};

    short8 ah[2][MT];
    short8 al[MT];
#pragma unroll
    for (int mt = 0; mt < MT; ++mt)
      ah[0][mt] = *(const short8*)&Ah[(mt * 16 + l16) * KSTR + quad * 8];

#pragma unroll
    for (int kc = 0; kc < 4; ++kc) {
      const int cur = kc & 1;
      const int k0  = kc * 32 + quad * 8;
#pragma unroll
      for (int mt = 0; mt < MT; ++mt)
        al[mt] = *(const short8*)&Al[(mt * 16 + l16) * KSTR + k0];
      if (kc + 1 < 4) {
        const int k1 = k0 + 32;
#pragma unroll
        for (int mt = 0; mt < MT; ++mt)
          ah[cur ^ 1][mt] = *(const short8*)&Ah[(mt * 16 + l16) * KSTR + k1];
      }
      __builtin_amdgcn_s_setprio(1);
#pragma unroll
      for (int mt = 0; mt < MT; ++mt) {
        c[mt] = __builtin_amdgcn_mfma_f32_16x16x32_bf16(wh[kc], ah[cur][mt], c[mt], 0, 0, 0);
        c[mt] = __builtin_amdgcn_mfma_f32_16x16x32_bf16(wl[kc], ah[cur][mt], c[mt], 0, 0, 0);
        c[mt] = __builtin_amdgcn_mfma_f32_16x16x32_bf16(wh[kc], al[mt], c[mt], 0, 0, 0);
      }
      __builtin_amdgcn_s_setprio(0);
    }
#pragma unroll
    for (int mt = 0; mt < MT; ++mt) {
      const int m = mt * 16 + l16;
#pragma unroll
      for (int r = 0; r < 4; ++r) {
        const int n = nb + r;
        const float v = c[mt][r] + bvr[r];
        if (n < OUTC) {
          outH[m * 33 + n] = (unsigned short)(__float_as_uint(v) >> 16);
          outL[m * 33 + n] = f2bf_rne(v - trunc_bf(v));
        }
        if (finalOut && n == 0 && m == 0) *finalOut = v;
      }
    }
  }
}

__global__ __launch_bounds__(THREADS, 4)
void leaf_kernel(const float* __restrict__ X,
                 const unsigned short* __restrict__ warena,
                 const float* __restrict__ barena,
                 unsigned short* __restrict__ outH, unsigned short* __restrict__ outL)
{
  __shared__ unsigned short Ah[64 * KSTR];
  __shared__ unsigned short Al[64 * KSTR];
  const int row_base = blockIdx.x * 64;
  const int tid = threadIdx.x;

  for (int e = tid; e < 64 * 16; e += THREADS) {
    const int r  = e >> 4;
    const int k0 = (e & 15) << 2;
    const float4 v = *(const float4*)&X[(size_t)(row_base + r) * FLEAF + k0];
    const unsigned int h0 = pack_hi_trunc(v.x, v.y);
    const unsigned int h1 = pack_hi_trunc(v.z, v.w);
    const unsigned int l0 = pack_lo_rne(v.x - trunc_bf(v.x), v.y - trunc_bf(v.y));
    const unsigned int l1 = pack_lo_rne(v.z - trunc_bf(v.z), v.w - trunc_bf(v.w));
    *(uint2*)&Ah[r * KSTR + k0] = make_uint2(h0, h1);
    *(uint2*)&Al[r * KSTR + k0] = make_uint2(l0, l1);
  }
  __syncthreads();

  dense_layer<2, 4>(Ah, Al, warena + 0 * 2 * MATSZ, warena + 0 * 2 * MATSZ + MATSZ, barena + 0 * 128);
#pragma unroll
  for (int l = 0; l < 4; ++l) {
    const int id = 1 + l;
    dense_layer<4, 4>(Ah, Al, warena + id * 2 * MATSZ, warena + id * 2 * MATSZ + MATSZ, barena + id * 128);
  }
  out_layer<4>(Ah, Al, warena + 5 * 2 * MATSZ, warena + 5 * 2 * MATSZ + MATSZ, barena + 5 * 128,
               outH + (size_t)row_base * 33, outL + (size_t)row_base * 33, nullptr);
}

__global__ __launch_bounds__(THREADS, 4)
void int_kernel(const float* __restrict__ feat,
                const unsigned short* __restrict__ prevH, const unsigned short* __restrict__ prevL,
                const unsigned short* __restrict__ warena, const float* __restrict__ barena,
                unsigned short* __restrict__ outH, unsigned short* __restrict__ outL,
                int n, int logn)
{
  __shared__ unsigned short Ah[64 * KSTR];
  __shared__ unsigned short Al[64 * KSTR];
  const int tid  = threadIdx.x;
  const int row0 = blockIdx.x * 64;
  const int b    = row0 >> logn;       // n >= 64: whole block shares one batch b
  const int i0   = row0 & (n - 1);

  // feat: 64 contiguous rows x 32 floats -> flat coalesced float4 loads
  const float* fr0 = feat + ((size_t)b * NINT + (n - 1) + i0) * FINT;
#pragma unroll
  for (int j = 0; j < 2; ++j) {
    const int e  = tid + j * 256;                      // 0..511 float4s
    const int r  = e >> 3;
    const int cc = (e & 7) << 2;                       // k offset in floats/u16
    const float4 v = *(const float4*)&fr0[(size_t)e << 2];
    const unsigned int h0 = pack_hi_trunc(v.x, v.y);
    const unsigned int h1 = pack_hi_trunc(v.z, v.w);
    const unsigned int l0 = pack_lo_rne(v.x - trunc_bf(v.x), v.y - trunc_bf(v.y));
    const unsigned int l1 = pack_lo_rne(v.z - trunc_bf(v.z), v.w - trunc_bf(v.w));
    *(uint2*)&Ah[r * KSTR + cc] = make_uint2(h0, h1);
    *(uint2*)&Al[r * KSTR + cc] = make_uint2(l0, l1);
  }
  // children: block's 64 rows are 64*66 CONTIGUOUS u16 = 2112 u32 per array
  //  -> flat coalesced u32 loads, scatter into LDS rows (div-by-33 is magic-mul)
  const size_t cbase = ((size_t)b * (n << 1) + (size_t)(i0 << 1)) * 33;
  const unsigned int* srcH = (const unsigned int*)(prevH + cbase);
  const unsigned int* srcL = (const unsigned int*)(prevL + cbase);
#pragma unroll
  for (int j = 0; j < 9; ++j) {
    const int idx = tid + j * 256;                     // 0..2303
    if (idx < 2112) {
      const unsigned int mm = (unsigned int)idx / 33u;
      const unsigned int pp = (unsigned int)idx - mm * 33u;
      *(unsigned int*)&Ah[mm * KSTR + 32 + 2 * pp] = srcH[idx];
      *(unsigned int*)&Al[mm * KSTR + 32 + 2 * pp] = srcL[idx];
    }
  }
  // zero-pad k = 98..127
  const int m = tid & 63;
  const int g = tid >> 6;
#pragma unroll
  for (int j = 0; j < 4; ++j) {
    const int p = g + 4 * j;                           // 0..15
    if (p < 15) {
      *(unsigned int*)&Ah[m * KSTR + 98 + 2 * p] = 0u;
      *(unsigned int*)&Al[m * KSTR + 98 + 2 * p] = 0u;
    }
  }
  __syncthreads();

  dense_layer<4, 4>(Ah, Al, warena + 6 * 2 * MATSZ, warena + 6 * 2 * MATSZ + MATSZ, barena + 6 * 128);
#pragma unroll
  for (int l = 0; l < 4; ++l) {
    const int id = 7 + l;
    dense_layer<4, 4>(Ah, Al, warena + id * 2 * MATSZ, warena + id * 2 * MATSZ + MATSZ, barena + id * 128);
  }
  out_layer<4>(Ah, Al, warena + 11 * 2 * MATSZ, warena + 11 * 2 * MATSZ + MATSZ, barena + 11 * 128,
               outH + (size_t)blockIdx.x * 64 * 33, outL + (size_t)blockIdx.x * 64 * 33, nullptr);
}

// Fused tail: levels d=5..0 for one batch per block; inter-level data in LDS.
__global__ __launch_bounds__(THREADS, 4)
void tail_kernel(const float* __restrict__ feat,
                 const unsigned short* __restrict__ g6H, const unsigned short* __restrict__ g6L,
                 const unsigned short* __restrict__ warena, const float* __restrict__ barena,
                 float* __restrict__ out)
{
  __shared__ unsigned short Ah[64 * KSTR];
  __shared__ unsigned short Al[64 * KSTR];
  __shared__ unsigned short oH[64 * 33];
  __shared__ unsigned short oL[64 * 33];
  const int tid = threadIdx.x;
  const int m = tid & 63;
  const int g = tid >> 6;
  const int b = blockIdx.x;

  for (int d = 5; d >= 0; --d) {
    const int n = 1 << d;
    const int i = m & (n - 1);          // clamp; junk rows compute harmless garbage
    const float* fr = feat + ((size_t)b * NINT + (n - 1) + i) * FINT;
#pragma unroll
    for (int j = 0; j < 4; ++j) {
      const int cch = g + 4 * j;
      const float2 v = *(const float2*)&fr[cch * 2];
      *(unsigned int*)&Ah[m * KSTR + cch * 2] = pack_hi_trunc(v.x, v.y);
      *(unsigned int*)&Al[m * KSTR + cch * 2] = pack_lo_rne(v.x - trunc_bf(v.x), v.y - trunc_bf(v.y));
    }
    const unsigned short* sH;
    const unsigned short* sL;
    size_t c0;
    if (d == 5) { sH = g6H; sL = g6L; c0 = ((size_t)b * 64 + 2 * i) * 33; }
    else        { sH = oH;  sL = oL;  c0 = (size_t)(2 * i) * 33; }
#pragma unroll
    for (int j = 0; j < 9; ++j) {
      const int p = g + 4 * j;
      if (p < 33) {
        const unsigned int hv = *(const unsigned int*)&sH[c0 + 2 * p];
        const unsigned int lv = *(const unsigned int*)&sL[c0 + 2 * p];
        *(unsigned int*)&Ah[m * KSTR + 32 + 2 * p] = hv;
        *(unsigned int*)&Al[m * KSTR + 32 + 2 * p] = lv;
      }
    }
#pragma unroll
    for (int j = 0; j < 4; ++j) {
      const int p = g + 4 * j;
      if (p < 15) {
        *(unsigned int*)&Ah[m * KSTR + 98 + 2 * p] = 0u;
        *(unsigned int*)&Al[m * KSTR + 98 + 2 * p] = 0u;
      }
    }
    __syncthreads();

    if (d == 5) {
      dense_layer<4, 2>(Ah, Al, warena + 6 * 2 * MATSZ, warena + 6 * 2 * MATSZ + MATSZ, barena + 6 * 128);
#pragma unroll
      for (int l = 0; l < 4; ++l) {
        const int id = 7 + l;
        dense_layer<4, 2>(Ah, Al, warena + id * 2 * MATSZ, warena + id * 2 * MATSZ + MATSZ, barena + id * 128);
      }
      out_layer<2>(Ah, Al, warena + 11 * 2 * MATSZ, warena + 11 * 2 * MATSZ + MATSZ, barena + 11 * 128,
                   oH, oL, nullptr);
    } else {
      dense_layer<4, 1>(Ah, Al, warena + 6 * 2 * MATSZ, warena + 6 * 2 * MATSZ + MATSZ, barena + 6 * 128);
#pragma unroll
      for (int l = 0; l < 4; ++l) {
        const int id = 7 + l;
        dense_layer<4, 1>(Ah, Al, warena + id * 2 * MATSZ, warena + id * 2 * MATSZ + MATSZ, barena + id * 128);
      }
      out_layer<1>(Ah, Al, warena + 11 * 2 * MATSZ, warena + 11 * 2 * MATSZ + MATSZ, barena + 11 * 128,
                   oH, oL, (d == 0) ? (out + b) : nullptr);
    }
    __syncthreads();   // out_layer reads/writes done before next staging
  }
}

// Pre-transpose + hi/lo split 12 weight matrices into WT[n][KSTR] (RNE both halves),
// pack biases zero-padded to 128.
__global__ void prep_kernel(const float* __restrict__ lW_in, const float* __restrict__ lW_hid,
                            const float* __restrict__ lW_out, const float* __restrict__ lb_in,
                            const float* __restrict__ lb_hid, const float* __restrict__ lb_out,
                            const float* __restrict__ iW_in, const float* __restrict__ iW_hid,
                            const float* __restrict__ iW_out, const float* __restrict__ ib_in,
                            const float* __restrict__ ib_hid, const float* __restrict__ ib_out,
                            unsigned short* __restrict__ warena, float* __restrict__ barena)
{
  const int id = blockIdx.y;
  const float* W; const float* bs; int K, N;
  if (id == 0)       { W = lW_in;                        bs = lb_in;                 K = FLEAF; N = Hh; }
  else if (id <= 4)  { W = lW_hid + (id - 1) * Hh * Hh;  bs = lb_hid + (id - 1) * Hh; K = Hh;   N = Hh; }
  else if (id == 5)  { W = lW_out;                       bs = lb_out;                K = Hh;    N = OUTC; }
  else if (id == 6)  { W = iW_in;                        bs = ib_in;                 K = FINT + 2 * OUTC; N = Hh; }
  else if (id <= 10) { W = iW_hid + (id - 7) * Hh * Hh;  bs = ib_hid + (id - 7) * Hh; K = Hh;   N = Hh; }
  else               { W = iW_out;                       bs = ib_out;                K = Hh;    N = OUTC; }

  unsigned short* dh = warena + id * 2 * MATSZ;
  unsigned short* dl = dh + MATSZ;
  const int e = blockIdx.x * THREADS + threadIdx.x;
  if (e < MATSZ) {
    const int nn = e / KSTR;
    const int kk = e - nn * KSTR;
    const float v = (kk < K && nn < N) ? W[(size_t)kk * N + nn] : 0.f;
    const unsigned short h = f2bf_rne(v);
    dh[e] = h;
    dl[e] = f2bf_rne(v - bf2f(h));
  }
  if (blockIdx.x == 0 && threadIdx.x < 128)
    barena[id * 128 + threadIdx.x] = (threadIdx.x < N) ? bs[threadIdx.x] : 0.f;
}

extern "C" void kernel_launch(void* const* d_in, const int* in_sizes, int n_in,
                              void* d_out, int out_size, void* d_ws, size_t ws_size,
                              hipStream_t stream) {
  const float* leaf_feat = (const float*)d_in[0];
  const float* int_feat  = (const float*)d_in[1];
  const float* lW_in  = (const float*)d_in[2];
  const float* lb_in  = (const float*)d_in[3];
  const float* lW_hid = (const float*)d_in[4];
  const float* lb_hid = (const float*)d_in[5];
  const float* lW_out = (const float*)d_in[6];
  const float* lb_out = (const float*)d_in[7];
  const float* iW_in  = (const float*)d_in[8];
  const float* ib_in  = (const float*)d_in[9];
  const float* iW_hid = (const float*)d_in[10];
  const float* ib_hid = (const float*)d_in[11];
  const float* iW_out = (const float*)d_in[12];
  const float* ib_out = (const float*)d_in[13];
  float* out = (float*)d_out;

  // ws layout (u16 hi/lo stage buffers, stride 33):
  //  A: 524288 rows (leaf out / d8 out / d6 out), B: 262144 rows (d9 out / d7 out)
  const size_t rowsA = (size_t)Bn * LEAVES;       // 524288
  const size_t rowsB = rowsA / 2;                 // 262144
  unsigned short* AH = (unsigned short*)d_ws;
  unsigned short* AL = AH + rowsA * 33;
  unsigned short* BH = AL + rowsA * 33;
  unsigned short* BL = BH + rowsB * 33;
  unsigned short* warena = BL + rowsB * 33;
  float* barena = (float*)(warena + 24 * MATSZ);  // total ~104.7 MB

  prep_kernel<<<dim3((MATSZ + THREADS - 1) / THREADS, 12), THREADS, 0, stream>>>(
      lW_in, lW_hid, lW_out, lb_in, lb_hid, lb_out,
      iW_in, iW_hid, iW_out, ib_in, ib_hid, ib_out, warena, barena);

  leaf_kernel<<<(Bn * LEAVES) / 64, THREADS, 0, stream>>>(leaf_feat, warena, barena, AH, AL);

  int_kernel<<<4096, THREADS, 0, stream>>>(int_feat, AH, AL, warena, barena, BH, BL, 512, 9);
  int_kernel<<<2048, THREADS, 0, stream>>>(int_feat, BH, BL, warena, barena, AH, AL, 256, 8);
  int_kernel<<<1024, THREADS, 0, stream>>>(int_feat, AH, AL, warena, barena, BH, BL, 128, 7);
  int_kernel<<< 512, THREADS, 0, stream>>>(int_feat, BH, BL, warena, barena, AH, AL,  64, 6);

  tail_kernel<<<Bn, THREADS, 0, stream>>>(int_feat, AH, AL, warena, barena, out);
}

// Round 4
// 903.829 us; speedup vs baseline: 1.6180x; 1.6180x over previous
//
#include <hip/hip_runtime.h>
#include <cstdint>
#include <cstddef>

// ---- problem constants ----
constexpr int Bn     = 512;
constexpr int Dd     = 11;
constexpr int LEAVES = 1024;
constexpr int NINT   = 1023;
constexpr int FLEAF  = 64;
constexpr int FINT   = 32;
constexpr int Hh     = 128;
constexpr int OUTC   = 33;

#define THREADS 256
constexpr int KSTR  = 136;            // LDS/weight k-stride (u16): 272B rows, 16B aligned
constexpr int MATSZ = 128 * KSTR;     // u16 per half-matrix (hi or lo)

using short8 = __attribute__((ext_vector_type(8))) short;
using f32x4  = __attribute__((ext_vector_type(4))) float;

__device__ __forceinline__ unsigned int f2bf_rne_u(float f) {
  unsigned int u = __float_as_uint(f);
  u += 0x7fffu + ((u >> 16) & 1);
  return u;                            // bf16 in hi16
}
__device__ __forceinline__ unsigned short f2bf_rne(float f) {
  return (unsigned short)(f2bf_rne_u(f) >> 16);
}
__device__ __forceinline__ float bf2f(unsigned short h) {
  return __uint_as_float((unsigned int)h << 16);
}
__device__ __forceinline__ float trunc_bf(float a) {
  return __uint_as_float(__float_as_uint(a) & 0xffff0000u);
}
// hi(trunc) of a -> lo16, hi(trunc) of b -> hi16
__device__ __forceinline__ unsigned int pack_hi_trunc(float a, float b) {
  return (__float_as_uint(a) >> 16) | (__float_as_uint(b) & 0xffff0000u);
}
// RNE-bf16 of a -> lo16, RNE-bf16 of b -> hi16 (HW packed convert, 1 instr).
// Epilogue-only change vs round-0: same dataflow, fewer VALU ops, no reg-pressure delta.
__device__ __forceinline__ unsigned int pack_lo_rne(float a, float b) {
  unsigned int r;
  asm("v_cvt_pk_bf16_f32 %0, %1, %2" : "=v"(r) : "v"(a), "v"(b));
  return r;
}

// Swapped-operand dense layer: D = W_tile x Act^T.  (round-0 proven version:
// 64 arch VGPR + ~60 acc regs = just under the 128-total / 4-blocks-per-CU cliff.
// Do NOT add live state here: round 1 (W-preload) lost a block (occ 30), round 2
// (same + bounds 4) spilled to scratch (1.2 GB/dispatch). The cliff is real.)
template <int KC, int MT>
__device__ __forceinline__ void dense_layer(
    unsigned short* Ah, unsigned short* Al,
    const unsigned short* __restrict__ WTh, const unsigned short* __restrict__ WTl,
    const float* __restrict__ bias)
{
  const int tid  = threadIdx.x;
  const int wave = tid >> 6;
  const int lane = tid & 63;
  const int quad = lane >> 4;
  const int l16  = lane & 15;
  const int nbase = wave * 32;

  // preload W-hi fragments (8 frags = 32 VGPR for KC=4) + bias
  short8 wh[2][KC];
#pragma unroll
  for (int nt = 0; nt < 2; ++nt) {
    const int n = nbase + nt * 16 + l16;
#pragma unroll
    for (int kc = 0; kc < KC; ++kc)
      wh[nt][kc] = *(const short8*)&WTh[n * KSTR + kc * 32 + quad * 8];
  }
  float4 bv[2];
#pragma unroll
  for (int nt = 0; nt < 2; ++nt)
    bv[nt] = *(const float4*)&bias[nbase + nt * 16 + quad * 4];

  f32x4 c[MT][2];
#pragma unroll
  for (int mt = 0; mt < MT; ++mt)
#pragma unroll
    for (int nt = 0; nt < 2; ++nt) c[mt][nt] = (f32x4){0.f, 0.f, 0.f, 0.f};

#pragma unroll
  for (int kc = 0; kc < KC; ++kc) {
    const int k0 = kc * 32 + quad * 8;
    short8 wl[2];
#pragma unroll
    for (int nt = 0; nt < 2; ++nt) {
      const int n = nbase + nt * 16 + l16;
      wl[nt] = *(const short8*)&WTl[n * KSTR + k0];
    }
    short8 ah[MT], al[MT];
#pragma unroll
    for (int mt = 0; mt < MT; ++mt) {
      ah[mt] = *(const short8*)&Ah[(mt * 16 + l16) * KSTR + k0];
      al[mt] = *(const short8*)&Al[(mt * 16 + l16) * KSTR + k0];
    }
    // grouped by term: consecutive MFMAs independent across tiles
#pragma unroll
    for (int mt = 0; mt < MT; ++mt)
#pragma unroll
      for (int nt = 0; nt < 2; ++nt)
        c[mt][nt] = __builtin_amdgcn_mfma_f32_16x16x32_bf16(wh[nt][kc], ah[mt], c[mt][nt], 0, 0, 0);
#pragma unroll
    for (int mt = 0; mt < MT; ++mt)
#pragma unroll
      for (int nt = 0; nt < 2; ++nt)
        c[mt][nt] = __builtin_amdgcn_mfma_f32_16x16x32_bf16(wh[nt][kc], al[mt], c[mt][nt], 0, 0, 0);
#pragma unroll
    for (int mt = 0; mt < MT; ++mt)
#pragma unroll
      for (int nt = 0; nt < 2; ++nt)
        c[mt][nt] = __builtin_amdgcn_mfma_f32_16x16x32_bf16(wl[nt], ah[mt], c[mt][nt], 0, 0, 0);
  }
  __syncthreads();  // all reads of Ah/Al done before in-place overwrite

#pragma unroll
  for (int mt = 0; mt < MT; ++mt) {
    const int m = mt * 16 + l16;
#pragma unroll
    for (int nt = 0; nt < 2; ++nt) {
      const int nb = nbase + nt * 16 + quad * 4;
      float v0 = fmaxf(c[mt][nt][0] + bv[nt].x, 0.f);
      float v1 = fmaxf(c[mt][nt][1] + bv[nt].y, 0.f);
      float v2 = fmaxf(c[mt][nt][2] + bv[nt].z, 0.f);
      float v3 = fmaxf(c[mt][nt][3] + bv[nt].w, 0.f);
      const unsigned int h0 = pack_hi_trunc(v0, v1);
      const unsigned int h1 = pack_hi_trunc(v2, v3);
      const unsigned int l0 = pack_lo_rne(v0 - trunc_bf(v0), v1 - trunc_bf(v1));
      const unsigned int l1 = pack_lo_rne(v2 - trunc_bf(v2), v3 - trunc_bf(v3));
      *(uint2*)&Ah[m * KSTR + nb] = make_uint2(h0, h1);
      *(uint2*)&Al[m * KSTR + nb] = make_uint2(l0, l1);
    }
  }
  __syncthreads();
}

// Output layer: [M x 128] @ [128 x 33] + bias (linear). Writes u16 hi/lo rows (stride 33)
// to outH/outL; if finalOut != nullptr, also writes per-row fp32 scalar (n==0 column):
// finalOut[m] = v  (used by the last tree level, where global row == batch index).
template <int MT>
__device__ __forceinline__ void out_layer(
    const unsigned short* Ah, const unsigned short* Al,
    const unsigned short* __restrict__ WTh, const unsigned short* __restrict__ WTl,
    const float* __restrict__ bias,
    unsigned short* outH, unsigned short* outL, float* finalOut)
{
  const int tid  = threadIdx.x;
  const int wave = tid >> 6;
  const int lane = tid & 63;
  const int quad = lane >> 4;
  const int l16  = lane & 15;
  if (wave < 3) {                       // 48 padded cols cover 33
    const int n_row = wave * 16 + l16;
    short8 wh[4], wl[4];
#pragma unroll
    for (int kc = 0; kc < 4; ++kc) {
      wh[kc] = *(const short8*)&WTh[n_row * KSTR + kc * 32 + quad * 8];
      wl[kc] = *(const short8*)&WTl[n_row * KSTR + kc * 32 + quad * 8];
    }
    const int nb = wave * 16 + quad * 4;
    const float4 bv = *(const float4*)&bias[nb];
    const float bvr[4] = {bv.x, bv.y, bv.z, bv.w};

    f32x4 c[MT];
#pragma unroll
    for (int mt = 0; mt < MT; ++mt) c[mt] = (f32x4){0.f, 0.f, 0.f, 0.f};
#pragma unroll
    for (int kc = 0; kc < 4; ++kc) {
      const int k0 = kc * 32 + quad * 8;
#pragma unroll
      for (int mt = 0; mt < MT; ++mt) {
        const short8 ah = *(const short8*)&Ah[(mt * 16 + l16) * KSTR + k0];
        const short8 al = *(const short8*)&Al[(mt * 16 + l16) * KSTR + k0];
        c[mt] = __builtin_amdgcn_mfma_f32_16x16x32_bf16(wh[kc], ah, c[mt], 0, 0, 0);
        c[mt] = __builtin_amdgcn_mfma_f32_16x16x32_bf16(wh[kc], al, c[mt], 0, 0, 0);
        c[mt] = __builtin_amdgcn_mfma_f32_16x16x32_bf16(wl[kc], ah, c[mt], 0, 0, 0);
      }
    }
#pragma unroll
    for (int mt = 0; mt < MT; ++mt) {
      const int m = mt * 16 + l16;
#pragma unroll
      for (int r = 0; r < 4; ++r) {
        const int n = nb + r;
        const float v = c[mt][r] + bvr[r];
        if (n < OUTC) {
          outH[m * 33 + n] = (unsigned short)(__float_as_uint(v) >> 16);
          outL[m * 33 + n] = f2bf_rne(v - trunc_bf(v));
        }
        if (finalOut && n == 0) finalOut[m] = v;
      }
    }
  }
}

__global__ __launch_bounds__(THREADS, 4)
void leaf_kernel(const float* __restrict__ X,
                 const unsigned short* __restrict__ warena,
                 const float* __restrict__ barena,
                 unsigned short* __restrict__ outH, unsigned short* __restrict__ outL)
{
  __shared__ unsigned short Ah[64 * KSTR];
  __shared__ unsigned short Al[64 * KSTR];
  const int row_base = blockIdx.x * 64;
  const int tid = threadIdx.x;

  for (int e = tid; e < 64 * 16; e += THREADS) {
    const int r  = e >> 4;
    const int k0 = (e & 15) << 2;
    const float4 v = *(const float4*)&X[(size_t)(row_base + r) * FLEAF + k0];
    const unsigned int h0 = pack_hi_trunc(v.x, v.y);
    const unsigned int h1 = pack_hi_trunc(v.z, v.w);
    const unsigned int l0 = pack_lo_rne(v.x - trunc_bf(v.x), v.y - trunc_bf(v.y));
    const unsigned int l1 = pack_lo_rne(v.z - trunc_bf(v.z), v.w - trunc_bf(v.w));
    *(uint2*)&Ah[r * KSTR + k0] = make_uint2(h0, h1);
    *(uint2*)&Al[r * KSTR + k0] = make_uint2(l0, l1);
  }
  __syncthreads();

  dense_layer<2, 4>(Ah, Al, warena + 0 * 2 * MATSZ, warena + 0 * 2 * MATSZ + MATSZ, barena + 0 * 128);
#pragma unroll
  for (int l = 0; l < 4; ++l) {
    const int id = 1 + l;
    dense_layer<4, 4>(Ah, Al, warena + id * 2 * MATSZ, warena + id * 2 * MATSZ + MATSZ, barena + id * 128);
  }
  out_layer<4>(Ah, Al, warena + 5 * 2 * MATSZ, warena + 5 * 2 * MATSZ + MATSZ, barena + 5 * 128,
               outH + (size_t)row_base * 33, outL + (size_t)row_base * 33, nullptr);
}

// One tree level, batched across ALL batches: rows = Bn * n, 64 rows/block, every row
// real work (no garbage MFMA). Per-row staging (round-0 proven): valid for any n >= 1,
// including blocks spanning multiple batches (b derived per row).
// If finalOut != nullptr (n == 1 level): writes fp32 scalar per row (row == batch idx).
__global__ __launch_bounds__(THREADS, 4)
void int_kernel(const float* __restrict__ feat,
                const unsigned short* __restrict__ prevH, const unsigned short* __restrict__ prevL,
                const unsigned short* __restrict__ warena, const float* __restrict__ barena,
                unsigned short* __restrict__ outH, unsigned short* __restrict__ outL,
                float* __restrict__ finalOut,
                int n, int logn)
{
  __shared__ unsigned short Ah[64 * KSTR];
  __shared__ unsigned short Al[64 * KSTR];
  const int tid = threadIdx.x;
  const int m = tid & 63;
  const int g = tid >> 6;
  const int row = blockIdx.x * 64 + m;
  const int b = row >> logn;
  const int i = row & (n - 1);

  // feat: 32 fp32 -> 16 float2 chunks, convert + packed u32 LDS writes
  const float* fr = feat + ((size_t)b * NINT + (n - 1) + i) * FINT;
#pragma unroll
  for (int j = 0; j < 4; ++j) {
    const int cch = g + 4 * j;                         // 0..15
    const float2 v = *(const float2*)&fr[cch * 2];
    *(unsigned int*)&Ah[m * KSTR + cch * 2] = pack_hi_trunc(v.x, v.y);
    *(unsigned int*)&Al[m * KSTR + cch * 2] = pack_lo_rne(v.x - trunc_bf(v.x), v.y - trunc_bf(v.y));
  }
  // children: rows 2i,2i+1 are 66 contiguous u16 in prev (c0 always even -> u32 copies)
  const size_t c0 = ((size_t)b * (n << 1) + (i << 1)) * 33;
#pragma unroll
  for (int j = 0; j < 9; ++j) {
    const int p = g + 4 * j;                           // 0..35
    if (p < 33) {
      const unsigned int hv = *(const unsigned int*)&prevH[c0 + 2 * p];
      const unsigned int lv = *(const unsigned int*)&prevL[c0 + 2 * p];
      *(unsigned int*)&Ah[m * KSTR + 32 + 2 * p] = hv;
      *(unsigned int*)&Al[m * KSTR + 32 + 2 * p] = lv;
    }
  }
  // zero-pad k = 98..127
#pragma unroll
  for (int j = 0; j < 4; ++j) {
    const int p = g + 4 * j;                           // 0..15
    if (p < 15) {
      *(unsigned int*)&Ah[m * KSTR + 98 + 2 * p] = 0u;
      *(unsigned int*)&Al[m * KSTR + 98 + 2 * p] = 0u;
    }
  }
  __syncthreads();

  dense_layer<4, 4>(Ah, Al, warena + 6 * 2 * MATSZ, warena + 6 * 2 * MATSZ + MATSZ, barena + 6 * 128);
#pragma unroll
  for (int l = 0; l < 4; ++l) {
    const int id = 7 + l;
    dense_layer<4, 4>(Ah, Al, warena + id * 2 * MATSZ, warena + id * 2 * MATSZ + MATSZ, barena + id * 128);
  }
  out_layer<4>(Ah, Al, warena + 11 * 2 * MATSZ, warena + 11 * 2 * MATSZ + MATSZ, barena + 11 * 128,
               outH + (size_t)blockIdx.x * 64 * 33, outL + (size_t)blockIdx.x * 64 * 33,
               finalOut ? (finalOut + blockIdx.x * 64) : nullptr);
}

// Pre-transpose + hi/lo split 12 weight matrices into WT[n][KSTR] (RNE both halves),
// pack biases zero-padded to 128.
__global__ void prep_kernel(const float* __restrict__ lW_in, const float* __restrict__ lW_hid,
                            const float* __restrict__ lW_out, const float* __restrict__ lb_in,
                            const float* __restrict__ lb_hid, const float* __restrict__ lb_out,
                            const float* __restrict__ iW_in, const float* __restrict__ iW_hid,
                            const float* __restrict__ iW_out, const float* __restrict__ ib_in,
                            const float* __restrict__ ib_hid, const float* __restrict__ ib_out,
                            unsigned short* __restrict__ warena, float* __restrict__ barena)
{
  const int id = blockIdx.y;
  const float* W; const float* bs; int K, N;
  if (id == 0)       { W = lW_in;                        bs = lb_in;                 K = FLEAF; N = Hh; }
  else if (id <= 4)  { W = lW_hid + (id - 1) * Hh * Hh;  bs = lb_hid + (id - 1) * Hh; K = Hh;   N = Hh; }
  else if (id == 5)  { W = lW_out;                       bs = lb_out;                K = Hh;    N = OUTC; }
  else if (id == 6)  { W = iW_in;                        bs = ib_in;                 K = FINT + 2 * OUTC; N = Hh; }
  else if (id <= 10) { W = iW_hid + (id - 7) * Hh * Hh;  bs = ib_hid + (id - 7) * Hh; K = Hh;   N = Hh; }
  else               { W = iW_out;                       bs = ib_out;                K = Hh;    N = OUTC; }

  unsigned short* dh = warena + id * 2 * MATSZ;
  unsigned short* dl = dh + MATSZ;
  const int e = blockIdx.x * THREADS + threadIdx.x;
  if (e < MATSZ) {
    const int nn = e / KSTR;
    const int kk = e - nn * KSTR;
    const float v = (kk < K && nn < N) ? W[(size_t)kk * N + nn] : 0.f;
    const unsigned short h = f2bf_rne(v);
    dh[e] = h;
    dl[e] = f2bf_rne(v - bf2f(h));
  }
  if (blockIdx.x == 0 && threadIdx.x < 128)
    barena[id * 128 + threadIdx.x] = (threadIdx.x < N) ? bs[threadIdx.x] : 0.f;
}

extern "C" void kernel_launch(void* const* d_in, const int* in_sizes, int n_in,
                              void* d_out, int out_size, void* d_ws, size_t ws_size,
                              hipStream_t stream) {
  const float* leaf_feat = (const float*)d_in[0];
  const float* int_feat  = (const float*)d_in[1];
  const float* lW_in  = (const float*)d_in[2];
  const float* lb_in  = (const float*)d_in[3];
  const float* lW_hid = (const float*)d_in[4];
  const float* lb_hid = (const float*)d_in[5];
  const float* lW_out = (const float*)d_in[6];
  const float* lb_out = (const float*)d_in[7];
  const float* iW_in  = (const float*)d_in[8];
  const float* ib_in  = (const float*)d_in[9];
  const float* iW_hid = (const float*)d_in[10];
  const float* ib_hid = (const float*)d_in[11];
  const float* iW_out = (const float*)d_in[12];
  const float* ib_out = (const float*)d_in[13];
  float* out = (float*)d_out;

  // ws layout (u16 hi/lo stage buffers, stride 33):
  //  A: 524288 rows, B: 262144 rows; levels ping-pong A<->B.
  const size_t rowsA = (size_t)Bn * LEAVES;       // 524288
  const size_t rowsB = rowsA / 2;                 // 262144
  unsigned short* AH = (unsigned short*)d_ws;
  unsigned short* AL = AH + rowsA * 33;
  unsigned short* BH = AL + rowsA * 33;
  unsigned short* BL = BH + rowsB * 33;
  unsigned short* warena = BL + rowsB * 33;
  float* barena = (float*)(warena + 24 * MATSZ);  // total ~104.7 MB

  prep_kernel<<<dim3((MATSZ + THREADS - 1) / THREADS, 12), THREADS, 0, stream>>>(
      lW_in, lW_hid, lW_out, lb_in, lb_hid, lb_out,
      iW_in, iW_hid, iW_out, ib_in, ib_hid, ib_out, warena, barena);

  leaf_kernel<<<(Bn * LEAVES) / 64, THREADS, 0, stream>>>(leaf_feat, warena, barena, AH, AL);

  // All 10 interior levels batched across batches; 64 real rows per block.
  // d:     9     8     7     6     5    4    3    2    1    0
  // grid: 4096  2048  1024  512   256  128  64   32   16   8
  int_kernel<<<4096, THREADS, 0, stream>>>(int_feat, AH, AL, warena, barena, BH, BL, nullptr, 512, 9);
  int_kernel<<<2048, THREADS, 0, stream>>>(int_feat, BH, BL, warena, barena, AH, AL, nullptr, 256, 8);
  int_kernel<<<1024, THREADS, 0, stream>>>(int_feat, AH, AL, warena, barena, BH, BL, nullptr, 128, 7);
  int_kernel<<< 512, THREADS, 0, stream>>>(int_feat, BH, BL, warena, barena, AH, AL, nullptr,  64, 6);
  int_kernel<<< 256, THREADS, 0, stream>>>(int_feat, AH, AL, warena, barena, BH, BL, nullptr,  32, 5);
  int_kernel<<< 128, THREADS, 0, stream>>>(int_feat, BH, BL, warena, barena, AH, AL, nullptr,  16, 4);
  int_kernel<<<  64, THREADS, 0, stream>>>(int_feat, AH, AL, warena, barena, BH, BL, nullptr,   8, 3);
  int_kernel<<<  32, THREADS, 0, stream>>>(int_feat, BH, BL, warena, barena, AH, AL, nullptr,   4, 2);
  int_kernel<<<  16, THREADS, 0, stream>>>(int_feat, AH, AL, warena, barena, BH, BL, nullptr,   2, 1);
  int_kernel<<<   8, THREADS, 0, stream>>>(int_feat, BH, BL, warena, barena, AH, AL, out,        1, 0);
}